// Round 10
// baseline (2511.176 us; speedup 1.0000x reference)
//
#include <hip/hip_runtime.h>
#include <hip/hip_fp16.h>
#include <math.h>

#define T_STEPS 128
#define B_SZ 256
#define AD 16
#define ZD 32
#define KM 8
#define HID 128
#define G4H 512
#define NTHR 512
#define LDW 36   // padded stride (dwords) for 32-col fp32 matrices, 16B aligned
#define LDC 20   // padded stride for 16-col rows (Kk, CPT), 16B aligned

// ws layout (4-byte word offsets)
// WS_WQ: 48*512*4 u32, packed f16 pairs, [d4][thread j][m]
//   d4  0..15 : W_hh0 row j; 16..31 : W_ih1 row j; 32..47 : W_hh1 row j
#define WS_WQ   0
#define WS_WI0  98304     // 8*512 u32 : W_ih0 row j packed pairs, [k][j]
#define WS_BS0  102400    // 512  b_ih0+b_hh0
#define WS_BS1  102912    // 512  b_ih1+b_hh1
#define WS_Q    103424    // 1024 Q = QL QL^T + 1e-3 I
#define WS_R    104448    // 256  R = RL RL^T + 1e-3 I

typedef float f32x4 __attribute__((ext_vector_type(4)));

__device__ __forceinline__ unsigned pk16(float lo, float hi) {
  unsigned a = __half_as_ushort(__float2half_rn(lo));
  unsigned b = __half_as_ushort(__float2half_rn(hi));
  return a | (b << 16);
}

__global__ void ssm_prep_kernel(const float* __restrict__ Wih0, const float* __restrict__ Whh0,
                                const float* __restrict__ Wih1, const float* __restrict__ Whh1,
                                const float* __restrict__ bih0, const float* __restrict__ bhh0,
                                const float* __restrict__ bih1, const float* __restrict__ bhh1,
                                const float* __restrict__ QL, const float* __restrict__ RL,
                                float* __restrict__ ws) {
  unsigned* wsu = (unsigned*)ws;
  int tid = blockIdx.x * blockDim.x + threadIdx.x;
  int nt = gridDim.x * blockDim.x;
  for (int j = tid; j < G4H; j += nt) {
    for (int d4 = 0; d4 < 48; ++d4) {
      for (int m = 0; m < 4; ++m) {
        int dd = (d4 & 15) * 4 + m;
        const float* src = (d4 < 16) ? Whh0 : (d4 < 32) ? Wih1 : Whh1;
        wsu[WS_WQ + (d4 * 512 + j) * 4 + m] =
            pk16(src[j * 128 + 2 * dd], src[j * 128 + 2 * dd + 1]);
      }
    }
    for (int k = 0; k < 8; ++k)
      wsu[WS_WI0 + k * 512 + j] = pk16(Wih0[j * 16 + 2 * k], Wih0[j * 16 + 2 * k + 1]);
    ws[WS_BS0 + j] = bih0[j] + bhh0[j];
    ws[WS_BS1 + j] = bih1[j] + bhh1[j];
  }
  for (int e = tid; e < ZD * ZD; e += nt) {
    int i = e >> 5, j = e & 31;
    float s = 0.f;
    for (int k = 0; k < ZD; ++k) s += QL[i * ZD + k] * QL[j * ZD + k];
    if (i == j) s += 0.001f;
    ws[WS_Q + e] = s;
  }
  for (int e = tid; e < AD * AD; e += nt) {
    int i = e >> 4, j = e & 15;
    float s = 0.f;
    for (int k = 0; k < AD; ++k) s += RL[i * AD + k] * RL[j * AD + k];
    if (i == j) s += 0.001f;
    ws[WS_R + e] = s;
  }
}

struct alignas(16) BS {
  unsigned ap[8];            // a_t packed f16 pairs
  float af[AD];              // a_t f32
  unsigned h0p[64];          // h0 packed f16 pairs
  unsigned h1p[64];
  float g[G4H];              // gates
  float lgp[16];             // logit partials
  float meanp[ZD], meant[ZD], r[AD];
  float P[ZD * LDW];         // cov_p (EXACTLY symmetric by construction)
  float An[ZD * LDW];        // A_next
  float Mt[ZD * LDW];        // cov_t (unsym), rows
  float MtT[ZD * LDW];       // cov_t transpose, rows = Mt columns
  float ACt[ZD * LDW];       // A_next @ sym(cov_t)
  float C[AD * LDW];
  float CP[AD * LDW];        // C @ P, rows (16x32)
  float CPT[ZD * LDC];       // (C @ P)^T, rows (32x16)
  float Kk[ZD * LDC];        // K row-major 32x16
  float SA[AD * 17];         // S
};

__device__ __forceinline__ float sigm(float x) { return 1.0f / (1.0f + expf(-x)); }
__device__ __forceinline__ float dotv(f32x4 a, f32x4 b) {
  return a[0] * b[0] + a[1] * b[1] + a[2] * b[2] + a[3] * b[3];
}
__device__ __forceinline__ void st_nt(float* p, float v) { __builtin_nontemporal_store(v, p); }
__device__ __forceinline__ void st_nt4(float* p, f32x4 v) {
  __builtin_nontemporal_store(v, (f32x4*)p);
}

__device__ __forceinline__ float dot2f(unsigned a, unsigned b, float c) {
#if __has_builtin(__builtin_amdgcn_fdot2)
  typedef _Float16 h2 __attribute__((ext_vector_type(2)));
  union U { unsigned u; h2 h; };
  U ua, ub; ua.u = a; ub.u = b;
  return __builtin_amdgcn_fdot2(ua.h, ub.h, c, false);
#else
  union U { unsigned u; _Float16 h[2]; };
  U ua, ub; ua.u = a; ub.u = b;
  return c + (float)ua.h[0] * (float)ub.h[0] + (float)ua.h[1] * (float)ub.h[1];
#endif
}

__global__ void __launch_bounds__(NTHR, 1) ssm_main_kernel(
    const float* __restrict__ as_, const float* __restrict__ AK, const float* __restrict__ CK,
    const float* __restrict__ initm, const float* __restrict__ initc,
    const float* __restrict__ Wout, const float* __restrict__ bout,
    const float* __restrict__ ws, float* __restrict__ out) {
  __shared__ BS s;
  const int tid = threadIdx.x;
  const int b = blockIdx.x;
  const unsigned* wsu = (const unsigned*)ws;
  const uint4* Wg = (const uint4*)(wsu + WS_WQ);
  const f32x4* AK4 = (const f32x4*)AK;
  const f32x4* CK4 = (const f32x4*)CK;

  float* o_means = out;
  float* o_covs = o_means + (size_t)T_STEPS * B_SZ * ZD;
  float* o_nmean = o_covs + (size_t)T_STEPS * B_SZ * ZD * ZD;
  float* o_ncovs = o_nmean + (size_t)T_STEPS * B_SZ * ZD;
  float* o_As = o_ncovs + (size_t)T_STEPS * B_SZ * ZD * ZD;
  float* o_Cs = o_As + (size_t)(T_STEPS + 1) * B_SZ * ZD * ZD;
  float* o_a = o_Cs + (size_t)(T_STEPS + 1) * B_SZ * AD * ZD;

  // LDS float4 views (row-chunk reads; all strides multiple of 4 dwords)
  f32x4* P4 = (f32x4*)s.P;         // stride 9
  f32x4* An4 = (f32x4*)s.An;
  f32x4* Mt4 = (f32x4*)s.Mt;
  f32x4* MtT4 = (f32x4*)s.MtT;
  f32x4* ACt4 = (f32x4*)s.ACt;
  f32x4* C4 = (f32x4*)s.C;
  f32x4* CP4 = (f32x4*)s.CP;
  f32x4* CPT4 = (f32x4*)s.CPT;     // stride 5
  f32x4* Kk4 = (f32x4*)s.Kk;       // stride 5
  const uint4* h0p4 = (const uint4*)s.h0p;
  const uint4* h1p4 = (const uint4*)s.h1p;
  const uint4* ap4 = (const uint4*)s.ap;
  const f32x4* r4 = (const f32x4*)s.r;
  const f32x4* meant4 = (const f32x4*)s.meant;
  const f32x4* meanp4 = (const f32x4*)s.meanp;

  // ---- thread-invariant register preloads ----
  unsigned wi0r[8];
  #pragma unroll
  for (int k = 0; k < 8; ++k) wi0r[k] = wsu[WS_WI0 + k * 512 + tid];
  // Layer-1 weights persistent in registers: W_ih1 + W_hh1 rows of thread `tid`
  // = 32 uint4 = 128 VGPRs, compile-time indexed (needs the 256-VGPR cap from
  // __launch_bounds__(512,1); with (512,2) these spilled -> round-9 regression)
  uint4 w2r[16];  // W_ih1
  uint4 w1r[16];  // W_hh1
  #pragma unroll
  for (int d4 = 0; d4 < 16; ++d4) {
    w2r[d4] = Wg[(16 + d4) * 512 + tid];
    w1r[d4] = Wg[(32 + d4) * 512 + tid];
  }
  const float bs0r = ws[WS_BS0 + tid];
  const float bs1r = ws[WS_BS1 + tid];
  const float Qr0 = ws[WS_Q + tid];
  const float Qr1 = ws[WS_Q + tid + NTHR];
  const float Rr = (tid < AD * AD) ? ws[WS_R + tid] : 0.f;
  float woutr[8];
  #pragma unroll
  for (int gi = 0; gi < KM; ++gi) woutr[gi] = (tid < HID) ? Wout[gi * HID + tid] : 0.f;
  float boutr[8];
  #pragma unroll
  for (int k = 0; k < KM; ++k) boutr[k] = bout[k];

  float c0r = 0.f, c1r = 0.f;

  // ---- init ----
  if (tid < 64) { s.h0p[tid] = 0u; s.h1p[tid] = 0u; }
  #pragma unroll
  for (int q = 0; q < 2; ++q) {
    int e = tid + q * NTHR;
    s.P[(e >> 5) * LDW + (e & 31)] = initc[e];
  }
  if (tid < ZD) s.meanp[tid] = initm[tid];
  if (tid < AD) {
    float v = as_[(size_t)b * AD + tid];
    s.af[tid] = v;
    ((__half*)s.ap)[tid] = __float2half_rn(v);
    st_nt(&o_a[(size_t)b * AD + tid], v);
  }
  if (tid < 256) {  // o_As[0] = sum_k AK[k] (w0 = ones)
    f32x4 acc = {0.f, 0.f, 0.f, 0.f};
    #pragma unroll
    for (int k = 0; k < KM; ++k) acc += AK4[k * 256 + tid];
    st_nt4(&o_As[(size_t)b * 1024 + tid * 4], acc);
  } else if (tid < 384) {  // C0 = sum_k CK[k]
    int idx = tid - 256;
    f32x4 acc = {0.f, 0.f, 0.f, 0.f};
    #pragma unroll
    for (int k = 0; k < KM; ++k) acc += CK4[k * 128 + idx];
    C4[(idx >> 3) * 9 + (idx & 7)] = acc;
    st_nt4(&o_Cs[(size_t)b * 512 + idx * 4], acc);
  }
  __syncthreads();

  for (int t = 0; t < T_STEPS; ++t) {
    const size_t tb = (size_t)t * B_SZ + b;
    const size_t tb2 = (size_t)(t + 1) * B_SZ + b;

    // ===== A: L0 gate + CP = C@P (P symmetric -> row dots) + r =====
    {
      float acc = bs0r;
      #pragma unroll
      for (int k4 = 0; k4 < 2; ++k4) {
        uint4 av = ap4[k4];
        acc = dot2f(av.x, wi0r[k4 * 4 + 0], acc);
        acc = dot2f(av.y, wi0r[k4 * 4 + 1], acc);
        acc = dot2f(av.z, wi0r[k4 * 4 + 2], acc);
        acc = dot2f(av.w, wi0r[k4 * 4 + 3], acc);
      }
      #pragma unroll
      for (int d4 = 0; d4 < 16; ++d4) {
        uint4 w = Wg[d4 * 512 + tid];
        uint4 hv = h0p4[d4];
        acc = dot2f(hv.x, w.x, acc);
        acc = dot2f(hv.y, w.y, acc);
        acc = dot2f(hv.z, w.z, acc);
        acc = dot2f(hv.w, w.w, acc);
      }
      s.g[tid] = acc;
    }
    {
      int i = tid >> 5, jj = tid & 31;
      float acc = 0.f;
      #pragma unroll
      for (int k4 = 0; k4 < 8; ++k4)
        acc += dotv(C4[i * 9 + k4], P4[jj * 9 + k4]);  // P row jj == column jj (symmetric)
      s.CP[i * LDW + jj] = acc;
      s.CPT[jj * LDC + i] = acc;
    }
    if (tid >= 480 && tid < 480 + AD) {
      int i = tid - 480;
      float acc = s.af[i];
      #pragma unroll
      for (int k4 = 0; k4 < 8; ++k4) acc -= dotv(C4[i * 9 + k4], meanp4[k4]);
      s.r[i] = acc;
    }
    __syncthreads();

    // ===== B: h0/c0 + S = CP C^T + R =====
    if (tid < HID) {
      float ig = sigm(s.g[tid]);
      float fg = sigm(s.g[HID + tid]);
      float gg = tanhf(s.g[2 * HID + tid]);
      float og = sigm(s.g[3 * HID + tid]);
      c0r = fg * c0r + ig * gg;
      ((__half*)s.h0p)[tid] = __float2half_rn(og * tanhf(c0r));
    }
    if (tid < AD * AD) {
      int i = tid >> 4, jj = tid & 15;
      float acc = Rr;
      #pragma unroll
      for (int m4 = 0; m4 < 8; ++m4) acc += dotv(CP4[i * 9 + m4], C4[jj * 9 + m4]);
      s.SA[i * 17 + jj] = acc;
    }
    __syncthreads();

    // ===== C: L1 gate (both matrices from registers — zero memory traffic) =====
    {
      float acc = bs1r;
      #pragma unroll
      for (int d4 = 0; d4 < 16; ++d4) {
        uint4 hv = h0p4[d4];
        acc = dot2f(hv.x, w2r[d4].x, acc);
        acc = dot2f(hv.y, w2r[d4].y, acc);
        acc = dot2f(hv.z, w2r[d4].z, acc);
        acc = dot2f(hv.w, w2r[d4].w, acc);
      }
      #pragma unroll
      for (int d4 = 0; d4 < 16; ++d4) {
        uint4 hv = h1p4[d4];
        acc = dot2f(hv.x, w1r[d4].x, acc);
        acc = dot2f(hv.y, w1r[d4].y, acc);
        acc = dot2f(hv.z, w1r[d4].z, acc);
        acc = dot2f(hv.w, w1r[d4].w, acc);
      }
      s.g[tid] = acc;
    }
    __syncthreads();

    // ===== D: [tid<128] h1/c1 + logits  |  [wave 7] register GJ -> K =====
    if (tid < HID) {
      float ig = sigm(s.g[tid]);
      float fg = sigm(s.g[HID + tid]);
      float gg = tanhf(s.g[2 * HID + tid]);
      float og = sigm(s.g[3 * HID + tid]);
      c1r = fg * c1r + ig * gg;
      float h1u = og * tanhf(c1r);
      ((__half*)s.h1p)[tid] = __float2half_rn(h1u);
      int w2 = tid >> 6, lane = tid & 63;
      #pragma unroll
      for (int gi = 0; gi < KM; ++gi) {
        float p = woutr[gi] * h1u;
        #pragma unroll
        for (int m = 32; m >= 1; m >>= 1) p += __shfl_xor(p, m);
        if (lane == 0) s.lgp[w2 * KM + gi] = p;
      }
    } else if (tid >= 448) {
      const int l = tid & 63;
      float col[16];
      #pragma unroll
      for (int i = 0; i < AD; ++i)
        col[i] = (l < AD) ? s.SA[i * 17 + l] : s.CP[i * LDW + ((l - AD) & 31)];
      #pragma unroll
      for (int j = 0; j < AD; ++j) {
        float pd = __shfl(col[j], j);
        float pinv = 1.0f / pd;
        float oldj = col[j];
        #pragma unroll
        for (int i = 0; i < AD; ++i) {
          if (i == j) continue;
          float fi = __shfl(col[i], j);
          col[i] = fmaf(-(fi * pinv), oldj, col[i]);
        }
        col[j] = oldj * pinv;
      }
      if (l >= AD && l < AD + ZD) {
        int rr = l - AD;  // K row rr
        f32x4 v0 = {col[0], col[1], col[2], col[3]};
        f32x4 v1 = {col[4], col[5], col[6], col[7]};
        f32x4 v2 = {col[8], col[9], col[10], col[11]};
        f32x4 v3 = {col[12], col[13], col[14], col[15]};
        Kk4[rr * 5 + 0] = v0;
        Kk4[rr * 5 + 1] = v1;
        Kk4[rr * 5 + 2] = v2;
        Kk4[rr * 5 + 3] = v3;
      }
    }
    __syncthreads();

    // ===== E: softmax + An/C_next einsums + mean_t + a prefetch =====
    {
      float lg[KM];
      float mx = -1e30f;
      #pragma unroll
      for (int k = 0; k < KM; ++k) {
        lg[k] = s.lgp[k] + s.lgp[KM + k] + boutr[k];
        mx = fmaxf(mx, lg[k]);
      }
      float sum = 0.f;
      #pragma unroll
      for (int k = 0; k < KM; ++k) { lg[k] = expf(lg[k] - mx); sum += lg[k]; }
      float inv = 1.0f / sum;
      #pragma unroll
      for (int k = 0; k < KM; ++k) lg[k] *= inv;
      if (tid < 256) {
        f32x4 acc = {0.f, 0.f, 0.f, 0.f};
        #pragma unroll
        for (int k = 0; k < KM; ++k) acc += lg[k] * AK4[k * 256 + tid];
        An4[(tid >> 3) * 9 + (tid & 7)] = acc;
        st_nt4(&o_As[tb2 * 1024 + tid * 4], acc);
      } else if (tid < 384) {
        int idx = tid - 256;
        f32x4 acc = {0.f, 0.f, 0.f, 0.f};
        #pragma unroll
        for (int k = 0; k < KM; ++k) acc += lg[k] * CK4[k * 128 + idx];
        C4[(idx >> 3) * 9 + (idx & 7)] = acc;
        st_nt4(&o_Cs[tb2 * 512 + idx * 4], acc);
      } else if (tid < 416) {
        int i = tid - 384;  // mean_t
        float acc = s.meanp[i];
        #pragma unroll
        for (int m = 0; m < 4; ++m) acc += dotv(Kk4[i * 5 + m], r4[m]);
        s.meant[i] = acc;
        st_nt(&o_means[tb * ZD + i], acc);
      } else if (tid < 432 && t < T_STEPS - 1) {
        int i = tid - 416;  // a_{t+1}
        float v = as_[tb2 * AD + i];
        s.af[i] = v;
        ((__half*)s.ap)[i] = __float2half_rn(v);
        st_nt(&o_a[tb2 * AD + i], v);
      }
    }
    __syncthreads();

    // ===== F: cov_t = P - K@CP -> Mt + MtT  +  meanp' = An@mean_t =====
    {
      int i0 = tid >> 5, i1 = i0 + 16, jj = tid & 31;
      f32x4 cpt[4];
      #pragma unroll
      for (int m = 0; m < 4; ++m) cpt[m] = CPT4[jj * 5 + m];  // CP column jj
      float a0 = 0.f, a1 = 0.f;
      #pragma unroll
      for (int m = 0; m < 4; ++m) {
        a0 += dotv(Kk4[i0 * 5 + m], cpt[m]);
        a1 += dotv(Kk4[i1 * 5 + m], cpt[m]);
      }
      float m0 = s.P[i0 * LDW + jj] - a0;
      float m1 = s.P[i1 * LDW + jj] - a1;
      s.Mt[i0 * LDW + jj] = m0;
      s.Mt[i1 * LDW + jj] = m1;
      s.MtT[jj * LDW + i0] = m0;
      s.MtT[jj * LDW + i1] = m1;
    }
    if (tid >= 480) {
      int i = tid - 480;  // i in [0,32)
      float acc = 0.f;
      #pragma unroll
      for (int m = 0; m < 8; ++m) acc += dotv(An4[i * 9 + m], meant4[m]);
      s.meanp[i] = acc;
      st_nt(&o_nmean[tb * ZD + i], acc);
    }
    __syncthreads();

    // ===== H: covs out = sym(Mt) (f32x4 NT) + ACt = An @ sym(Mt) (row dots) =====
    if (tid < 256) {
      int i = tid >> 3, j4 = tid & 7;
      f32x4 sym = 0.5f * (Mt4[i * 9 + j4] + MtT4[i * 9 + j4]);
      st_nt4(&o_covs[tb * 1024 + i * 32 + j4 * 4], sym);
    }
    {
      int i0 = tid >> 5, i1 = i0 + 16, jj = tid & 31;
      float acc0 = 0.f, acc1 = 0.f;
      #pragma unroll
      for (int k4 = 0; k4 < 8; ++k4) {
        // symMt row jj chunk k4 (symMt symmetric -> row == column)
        f32x4 sy = 0.5f * (Mt4[jj * 9 + k4] + MtT4[jj * 9 + k4]);
        acc0 += dotv(An4[i0 * 9 + k4], sy);
        acc1 += dotv(An4[i1 * 9 + k4], sy);
      }
      s.ACt[i0 * LDW + jj] = acc0;
      s.ACt[i1 * LDW + jj] = acc1;
    }
    __syncthreads();

    // ===== I: cov_p' = sym(ACt @ An^T) + Q -> P (fused, exact-symmetric) =====
    {
      int i0 = tid >> 5, i1 = i0 + 16, jj = tid & 31;
      float acc0 = 0.f, acc1 = 0.f;
      #pragma unroll
      for (int k4 = 0; k4 < 8; ++k4) {
        f32x4 anj = An4[jj * 9 + k4];
        f32x4 acj = ACt4[jj * 9 + k4];
        acc0 += dotv(ACt4[i0 * 9 + k4], anj) + dotv(acj, An4[i0 * 9 + k4]);
        acc1 += dotv(ACt4[i1 * 9 + k4], anj) + dotv(acj, An4[i1 * 9 + k4]);
      }
      float v0 = 0.5f * acc0 + Qr0;
      float v1 = 0.5f * acc1 + Qr1;
      s.P[i0 * LDW + jj] = v0;
      s.P[i1 * LDW + jj] = v1;
      st_nt(&o_ncovs[tb * 1024 + tid], v0);
      st_nt(&o_ncovs[tb * 1024 + tid + NTHR], v1);
    }
    __syncthreads();
  }
}

extern "C" void kernel_launch(void* const* d_in, const int* in_sizes, int n_in,
                              void* d_out, int out_size, void* d_ws, size_t ws_size,
                              hipStream_t stream) {
  const float* as_ = (const float*)d_in[0];
  const float* AK = (const float*)d_in[1];
  const float* CK = (const float*)d_in[2];
  const float* QL = (const float*)d_in[3];
  const float* RL = (const float*)d_in[4];
  const float* initm = (const float*)d_in[5];
  const float* initc = (const float*)d_in[6];
  const float* Wih0 = (const float*)d_in[7];
  const float* Whh0 = (const float*)d_in[8];
  const float* bih0 = (const float*)d_in[9];
  const float* bhh0 = (const float*)d_in[10];
  const float* Wih1 = (const float*)d_in[11];
  const float* Whh1 = (const float*)d_in[12];
  const float* bih1 = (const float*)d_in[13];
  const float* bhh1 = (const float*)d_in[14];
  const float* Wout = (const float*)d_in[15];
  const float* bout = (const float*)d_in[16];
  float* ws = (float*)d_ws;
  float* out = (float*)d_out;

  ssm_prep_kernel<<<16, 256, 0, stream>>>(Wih0, Whh0, Wih1, Whh1, bih0, bhh0, bih1, bhh1,
                                          QL, RL, ws);
  ssm_main_kernel<<<B_SZ, NTHR, 0, stream>>>(as_, AK, CK, initm, initc, Wout, bout, ws, out);
}

// Round 11
// 2238.425 us; speedup vs baseline: 1.1218x; 1.1218x over previous
//
#include <hip/hip_runtime.h>
#include <hip/hip_fp16.h>
#include <math.h>

#define T_STEPS 128
#define B_SZ 256
#define AD 16
#define ZD 32
#define KM 8
#define HID 128
#define G4H 512
#define NTHR 512

// ws layout (4-byte word offsets)
// WS_WQ: 48*512*4 u32, packed f16 pairs, [d4][thread j][m]
//   d4  0..15 : W_hh0 row j; 16..31 : W_ih1 row j; 32..47 : W_hh1 row j
#define WS_WQ   0
#define WS_WI0  98304     // 8*512 u32 : W_ih0 row j packed pairs, [k][j]
#define WS_BS0  102400    // 512  b_ih0+b_hh0
#define WS_BS1  102912    // 512  b_ih1+b_hh1
#define WS_Q    103424    // 1024 Q = QL QL^T + 1e-3 I
#define WS_R    104448    // 256  R = RL RL^T + 1e-3 I

typedef float f32x4 __attribute__((ext_vector_type(4)));

__device__ __forceinline__ unsigned pk16(float lo, float hi) {
  unsigned a = __half_as_ushort(__float2half_rn(lo));
  unsigned b = __half_as_ushort(__float2half_rn(hi));
  return a | (b << 16);
}

__global__ void ssm_prep_kernel(const float* __restrict__ Wih0, const float* __restrict__ Whh0,
                                const float* __restrict__ Wih1, const float* __restrict__ Whh1,
                                const float* __restrict__ bih0, const float* __restrict__ bhh0,
                                const float* __restrict__ bih1, const float* __restrict__ bhh1,
                                const float* __restrict__ QL, const float* __restrict__ RL,
                                float* __restrict__ ws) {
  unsigned* wsu = (unsigned*)ws;
  int tid = blockIdx.x * blockDim.x + threadIdx.x;
  int nt = gridDim.x * blockDim.x;
  for (int j = tid; j < G4H; j += nt) {
    for (int d4 = 0; d4 < 48; ++d4) {
      for (int m = 0; m < 4; ++m) {
        int dd = (d4 & 15) * 4 + m;
        const float* src = (d4 < 16) ? Whh0 : (d4 < 32) ? Wih1 : Whh1;
        wsu[WS_WQ + (d4 * 512 + j) * 4 + m] =
            pk16(src[j * 128 + 2 * dd], src[j * 128 + 2 * dd + 1]);
      }
    }
    for (int k = 0; k < 8; ++k)
      wsu[WS_WI0 + k * 512 + j] = pk16(Wih0[j * 16 + 2 * k], Wih0[j * 16 + 2 * k + 1]);
    ws[WS_BS0 + j] = bih0[j] + bhh0[j];
    ws[WS_BS1 + j] = bih1[j] + bhh1[j];
  }
  for (int e = tid; e < ZD * ZD; e += nt) {
    int i = e >> 5, j = e & 31;
    float s = 0.f;
    for (int k = 0; k < ZD; ++k) s += QL[i * ZD + k] * QL[j * ZD + k];
    if (i == j) s += 0.001f;
    ws[WS_Q + e] = s;
  }
  for (int e = tid; e < AD * AD; e += nt) {
    int i = e >> 4, j = e & 15;
    float s = 0.f;
    for (int k = 0; k < AD; ++k) s += RL[i * AD + k] * RL[j * AD + k];
    if (i == j) s += 0.001f;
    ws[WS_R + e] = s;
  }
}

__device__ __forceinline__ float sigm(float x) { return 1.0f / (1.0f + expf(-x)); }
__device__ __forceinline__ float dotv(f32x4 a, f32x4 b) {
  return a[0] * b[0] + a[1] * b[1] + a[2] * b[2] + a[3] * b[3];
}
__device__ __forceinline__ void st_nt(float* p, float v) { __builtin_nontemporal_store(v, p); }
__device__ __forceinline__ void st_nt4(float* p, f32x4 v) {
  __builtin_nontemporal_store(v, (f32x4*)p);
}

__device__ __forceinline__ float dot2f(unsigned a, unsigned b, float c) {
#if __has_builtin(__builtin_amdgcn_fdot2)
  typedef _Float16 h2 __attribute__((ext_vector_type(2)));
  union U { unsigned u; h2 h; };
  U ua, ub; ua.u = a; ub.u = b;
  return __builtin_amdgcn_fdot2(ua.h, ub.h, c, false);
#else
  union U { unsigned u; _Float16 h[2]; };
  U ua, ub; ua.u = a; ub.u = b;
  return c + (float)ua.h[0] * (float)ub.h[0] + (float)ua.h[1] * (float)ub.h[1];
#endif
}

// ============================ Kernel 1: LSTM chain ============================
struct alignas(16) LS {
  unsigned ap[8];
  unsigned h0p[64];
  unsigned h1p[64];
  float g[G4H];
  float lgp[16];
};

__global__ void __launch_bounds__(NTHR, 2) ssm_lstm_kernel(
    const float* __restrict__ as_, const float* __restrict__ AK, const float* __restrict__ CK,
    const float* __restrict__ Wout, const float* __restrict__ bout,
    const float* __restrict__ ws, float* __restrict__ out) {
  __shared__ LS s;
  const int tid = threadIdx.x;
  const int b = blockIdx.x;
  const unsigned* wsu = (const unsigned*)ws;
  const uint4* Wg = (const uint4*)(wsu + WS_WQ);
  const f32x4* AK4 = (const f32x4*)AK;
  const f32x4* CK4 = (const f32x4*)CK;

  float* o_As = out + (size_t)T_STEPS * B_SZ * ZD + (size_t)T_STEPS * B_SZ * ZD * ZD +
                (size_t)T_STEPS * B_SZ * ZD + (size_t)T_STEPS * B_SZ * ZD * ZD;
  float* o_Cs = o_As + (size_t)(T_STEPS + 1) * B_SZ * ZD * ZD;
  float* o_a = o_Cs + (size_t)(T_STEPS + 1) * B_SZ * AD * ZD;

  const uint4* h0p4 = (const uint4*)s.h0p;
  const uint4* h1p4 = (const uint4*)s.h1p;
  const uint4* ap4 = (const uint4*)s.ap;

  unsigned wi0r[8];
  #pragma unroll
  for (int k = 0; k < 8; ++k) wi0r[k] = wsu[WS_WI0 + k * 512 + tid];
  const float bs0r = ws[WS_BS0 + tid];
  const float bs1r = ws[WS_BS1 + tid];
  float woutr[8];
  #pragma unroll
  for (int gi = 0; gi < KM; ++gi) woutr[gi] = (tid < HID) ? Wout[gi * HID + tid] : 0.f;
  float boutr[8];
  #pragma unroll
  for (int k = 0; k < KM; ++k) boutr[k] = bout[k];

  float c0r = 0.f, c1r = 0.f;

  if (tid < 64) { s.h0p[tid] = 0u; s.h1p[tid] = 0u; }
  if (tid < AD) {
    float v = as_[(size_t)b * AD + tid];
    ((__half*)s.ap)[tid] = __float2half_rn(v);
    st_nt(&o_a[(size_t)b * AD + tid], v);
  }
  if (tid < 256) {  // o_As[0] (w0 = ones)
    f32x4 acc = {0.f, 0.f, 0.f, 0.f};
    #pragma unroll
    for (int k = 0; k < KM; ++k) acc += AK4[k * 256 + tid];
    st_nt4(&o_As[(size_t)b * 1024 + tid * 4], acc);
  } else if (tid < 384) {  // o_Cs[0]
    int idx = tid - 256;
    f32x4 acc = {0.f, 0.f, 0.f, 0.f};
    #pragma unroll
    for (int k = 0; k < KM; ++k) acc += CK4[k * 128 + idx];
    st_nt4(&o_Cs[(size_t)b * 512 + idx * 4], acc);
  }
  __syncthreads();

  for (int t = 0; t < T_STEPS; ++t) {
    const size_t tb2 = (size_t)(t + 1) * B_SZ + b;

    // A: L0 gates (stream W_hh0)
    {
      float acc = bs0r;
      #pragma unroll
      for (int k4 = 0; k4 < 2; ++k4) {
        uint4 av = ap4[k4];
        acc = dot2f(av.x, wi0r[k4 * 4 + 0], acc);
        acc = dot2f(av.y, wi0r[k4 * 4 + 1], acc);
        acc = dot2f(av.z, wi0r[k4 * 4 + 2], acc);
        acc = dot2f(av.w, wi0r[k4 * 4 + 3], acc);
      }
      #pragma unroll
      for (int d4 = 0; d4 < 16; ++d4) {
        uint4 w = Wg[d4 * 512 + tid];
        uint4 hv = h0p4[d4];
        acc = dot2f(hv.x, w.x, acc);
        acc = dot2f(hv.y, w.y, acc);
        acc = dot2f(hv.z, w.z, acc);
        acc = dot2f(hv.w, w.w, acc);
      }
      s.g[tid] = acc;
    }
    __syncthreads();

    // B: h0/c0
    if (tid < HID) {
      float ig = sigm(s.g[tid]);
      float fg = sigm(s.g[HID + tid]);
      float gg = tanhf(s.g[2 * HID + tid]);
      float og = sigm(s.g[3 * HID + tid]);
      c0r = fg * c0r + ig * gg;
      ((__half*)s.h0p)[tid] = __float2half_rn(og * tanhf(c0r));
    }
    __syncthreads();

    // C: L1 gates (stream W_ih1 + W_hh1)
    {
      float acc = bs1r;
      #pragma unroll
      for (int d4 = 0; d4 < 16; ++d4) {
        uint4 w = Wg[(16 + d4) * 512 + tid];
        uint4 hv = h0p4[d4];
        acc = dot2f(hv.x, w.x, acc);
        acc = dot2f(hv.y, w.y, acc);
        acc = dot2f(hv.z, w.z, acc);
        acc = dot2f(hv.w, w.w, acc);
      }
      #pragma unroll
      for (int d4 = 0; d4 < 16; ++d4) {
        uint4 w = Wg[(32 + d4) * 512 + tid];
        uint4 hv = h1p4[d4];
        acc = dot2f(hv.x, w.x, acc);
        acc = dot2f(hv.y, w.y, acc);
        acc = dot2f(hv.z, w.z, acc);
        acc = dot2f(hv.w, w.w, acc);
      }
      s.g[tid] = acc;
    }
    __syncthreads();

    // D: h1/c1 + logit partials
    if (tid < HID) {
      float ig = sigm(s.g[tid]);
      float fg = sigm(s.g[HID + tid]);
      float gg = tanhf(s.g[2 * HID + tid]);
      float og = sigm(s.g[3 * HID + tid]);
      c1r = fg * c1r + ig * gg;
      float h1u = og * tanhf(c1r);
      ((__half*)s.h1p)[tid] = __float2half_rn(h1u);
      int w2 = tid >> 6, lane = tid & 63;
      #pragma unroll
      for (int gi = 0; gi < KM; ++gi) {
        float p = woutr[gi] * h1u;
        #pragma unroll
        for (int m = 32; m >= 1; m >>= 1) p += __shfl_xor(p, m);
        if (lane == 0) s.lgp[w2 * KM + gi] = p;
      }
    }
    __syncthreads();

    // E: softmax + einsum outputs + a prefetch
    {
      float lg[KM];
      float mx = -1e30f;
      #pragma unroll
      for (int k = 0; k < KM; ++k) {
        lg[k] = s.lgp[k] + s.lgp[KM + k] + boutr[k];
        mx = fmaxf(mx, lg[k]);
      }
      float sum = 0.f;
      #pragma unroll
      for (int k = 0; k < KM; ++k) { lg[k] = expf(lg[k] - mx); sum += lg[k]; }
      float inv = 1.0f / sum;
      #pragma unroll
      for (int k = 0; k < KM; ++k) lg[k] *= inv;
      if (tid < 256) {
        f32x4 acc = {0.f, 0.f, 0.f, 0.f};
        #pragma unroll
        for (int k = 0; k < KM; ++k) acc += lg[k] * AK4[k * 256 + tid];
        st_nt4(&o_As[tb2 * 1024 + tid * 4], acc);
      } else if (tid < 384) {
        int idx = tid - 256;
        f32x4 acc = {0.f, 0.f, 0.f, 0.f};
        #pragma unroll
        for (int k = 0; k < KM; ++k) acc += lg[k] * CK4[k * 128 + idx];
        st_nt4(&o_Cs[tb2 * 512 + idx * 4], acc);
      } else if (tid >= 448 && tid < 448 + AD && t < T_STEPS - 1) {
        int i = tid - 448;
        float v = as_[tb2 * AD + i];
        ((__half*)s.ap)[i] = __float2half_rn(v);
        st_nt(&o_a[tb2 * AD + i], v);
      }
    }
    __syncthreads();
  }
}

// ===================== Kernel 2: Kalman chain (1 wave/batch) =====================
struct alignas(16) KS {
  float P[ZD * 36];      // cov_p (symmetric)
  float An[ZD * 36];     // A_next
  float Mt[ZD * 36];     // cov_t rows; reused for M2
  float MtT[ZD * 36];    // transposes
  float SymM[ZD * 36];   // sym(cov_t)
  float ACt[ZD * 36];
  float Qs[ZD * 36];
  float C[AD * 36];
  float CP[AD * 36];
  float CPT[ZD * 20];
  float Kk[ZD * 20];
  float Aug[AD * 52];    // [S | CP]
  float Rs[AD * AD];
  float meanp[ZD], meant[ZD], r[AD], af[AD];
};

__global__ void __launch_bounds__(64, 1) ssm_kalman_kernel(
    const float* __restrict__ as_, const float* __restrict__ initm,
    const float* __restrict__ initc, const float* __restrict__ ws,
    float* __restrict__ out) {
  __shared__ KS s;
  const int l = threadIdx.x;
  const int b = blockIdx.x;

  float* o_means = out;
  float* o_covs = o_means + (size_t)T_STEPS * B_SZ * ZD;
  float* o_nmean = o_covs + (size_t)T_STEPS * B_SZ * ZD * ZD;
  float* o_ncovs = o_nmean + (size_t)T_STEPS * B_SZ * ZD;
  const float* o_As = o_ncovs + (size_t)T_STEPS * B_SZ * ZD * ZD;
  const float* o_Cs = o_As + (size_t)(T_STEPS + 1) * B_SZ * ZD * ZD;

  f32x4* P4 = (f32x4*)s.P;        // stride 9
  f32x4* An4 = (f32x4*)s.An;
  f32x4* Mt4 = (f32x4*)s.Mt;
  f32x4* MtT4 = (f32x4*)s.MtT;
  f32x4* Sy4 = (f32x4*)s.SymM;
  f32x4* ACt4 = (f32x4*)s.ACt;
  f32x4* Q4 = (f32x4*)s.Qs;
  f32x4* C4 = (f32x4*)s.C;
  f32x4* CP4 = (f32x4*)s.CP;
  f32x4* CPT4 = (f32x4*)s.CPT;    // stride 5
  f32x4* Kk4 = (f32x4*)s.Kk;      // stride 5
  f32x4* af4 = (f32x4*)s.af;
  const f32x4* r4 = (const f32x4*)s.r;
  const f32x4* meanp4 = (const f32x4*)s.meanp;
  const f32x4* meant4 = (const f32x4*)s.meant;

  // init: P, meanp, Q (stride-36), R
  #pragma unroll
  for (int q = 0; q < 16; ++q) {
    int e = q * 64 + l;
    s.P[(e >> 5) * 36 + (e & 31)] = initc[e];
    s.Qs[(e >> 5) * 36 + (e & 31)] = ws[WS_Q + e];
  }
  #pragma unroll
  for (int q = 0; q < 4; ++q) s.Rs[q * 64 + l] = ws[WS_R + q * 64 + l];
  if (l < ZD) s.meanp[l] = initm[l];
  __syncthreads();

  for (int t = 0; t < T_STEPS; ++t) {
    const size_t tb = (size_t)t * B_SZ + b;

    // LOAD: C = o_Cs[t], An = o_As[t+1], a_t
    {
      const f32x4* gc = (const f32x4*)&o_Cs[tb * 512];
      #pragma unroll
      for (int q = 0; q < 2; ++q) {
        int idx = q * 64 + l;
        C4[(idx >> 3) * 9 + (idx & 7)] = gc[idx];
      }
      const f32x4* ga = (const f32x4*)&o_As[(tb + B_SZ) * 1024];
      #pragma unroll
      for (int q = 0; q < 4; ++q) {
        int idx = q * 64 + l;
        An4[(idx >> 3) * 9 + (idx & 7)] = ga[idx];
      }
      if (l < 4) af4[l] = ((const f32x4*)&as_[tb * AD])[l];
    }
    __syncthreads();

    // CP = C @ P (P symmetric -> row dots); fill CP, CPT, Aug right half
    {
      int i = l >> 2, jb = (l & 3) * 8;
      f32x4 cr[8];
      #pragma unroll
      for (int k4 = 0; k4 < 8; ++k4) cr[k4] = C4[i * 9 + k4];
      #pragma unroll
      for (int m = 0; m < 8; ++m) {
        int j = jb + m;
        float acc = 0.f;
        #pragma unroll
        for (int k4 = 0; k4 < 8; ++k4) acc += dotv(cr[k4], P4[j * 9 + k4]);
        s.CP[i * 36 + j] = acc;
        s.CPT[j * 20 + i] = acc;
        s.Aug[i * 52 + AD + j] = acc;
      }
    }
    __syncthreads();

    // S = CP C^T + R -> Aug left; r = a - C meanp (lanes 16..31)
    {
      int i = l >> 2;
      f32x4 cpr[8];
      #pragma unroll
      for (int k4 = 0; k4 < 8; ++k4) cpr[k4] = CP4[i * 9 + k4];
      #pragma unroll
      for (int m = 0; m < 4; ++m) {
        int j = (l & 3) * 4 + m;
        float acc = s.Rs[i * AD + j];
        #pragma unroll
        for (int k4 = 0; k4 < 8; ++k4) acc += dotv(cpr[k4], C4[j * 9 + k4]);
        s.Aug[i * 52 + j] = acc;
      }
      if (l >= 16 && l < 32) {
        int ii = l - 16;
        float acc = s.af[ii];
        #pragma unroll
        for (int k4 = 0; k4 < 8; ++k4) acc -= dotv(C4[ii * 9 + k4], meanp4[k4]);
        s.r[ii] = acc;
      }
    }
    __syncthreads();

    // GJ on [S | CP] -> K rows (wave-synchronous, register columns)
    {
      const int lc = (l < 48) ? l : 47;
      float col[16];
      #pragma unroll
      for (int i = 0; i < AD; ++i) col[i] = s.Aug[i * 52 + lc];
      #pragma unroll
      for (int j = 0; j < AD; ++j) {
        float pd = __shfl(col[j], j);
        float pinv = 1.0f / pd;
        float oldj = col[j];
        #pragma unroll
        for (int i = 0; i < AD; ++i) {
          if (i == j) continue;
          float fi = __shfl(col[i], j);
          col[i] = fmaf(-(fi * pinv), oldj, col[i]);
        }
        col[j] = oldj * pinv;
      }
      if (l >= AD && l < AD + ZD) {
        int rr = l - AD;
        f32x4 v0 = {col[0], col[1], col[2], col[3]};
        f32x4 v1 = {col[4], col[5], col[6], col[7]};
        f32x4 v2 = {col[8], col[9], col[10], col[11]};
        f32x4 v3 = {col[12], col[13], col[14], col[15]};
        Kk4[rr * 5 + 0] = v0;
        Kk4[rr * 5 + 1] = v1;
        Kk4[rr * 5 + 2] = v2;
        Kk4[rr * 5 + 3] = v3;
      }
    }
    __syncthreads();

    // mean_t (lanes<32) + cov_t = P - K@CP -> Mt, MtT
    {
      if (l < ZD) {
        float acc = s.meanp[l];
        #pragma unroll
        for (int m = 0; m < 4; ++m) acc += dotv(Kk4[l * 5 + m], r4[m]);
        s.meant[l] = acc;
        st_nt(&o_means[tb * ZD + l], acc);
      }
      int i = l >> 1, jb = (l & 1) * 16;
      f32x4 kr[4];
      #pragma unroll
      for (int m = 0; m < 4; ++m) kr[m] = Kk4[i * 5 + m];
      #pragma unroll
      for (int c = 0; c < 4; ++c) {
        f32x4 mv;
        #pragma unroll
        for (int mm = 0; mm < 4; ++mm) {
          int j = jb + c * 4 + mm;
          float acc = 0.f;
          #pragma unroll
          for (int m = 0; m < 4; ++m) acc += dotv(kr[m], CPT4[j * 5 + m]);
          mv[mm] = acc;
        }
        f32x4 pv = P4[i * 9 + (jb >> 2) + c];
        mv = pv - mv;
        Mt4[i * 9 + (jb >> 2) + c] = mv;
        #pragma unroll
        for (int mm = 0; mm < 4; ++mm) s.MtT[(jb + c * 4 + mm) * 36 + i] = mv[mm];
      }
    }
    __syncthreads();

    // symM = 0.5(Mt+MtT) -> SymM + covs out
    {
      int i = l >> 1, cb = (l & 1) * 4;
      #pragma unroll
      for (int c = 0; c < 4; ++c) {
        f32x4 sv = 0.5f * (Mt4[i * 9 + cb + c] + MtT4[i * 9 + cb + c]);
        Sy4[i * 9 + cb + c] = sv;
        st_nt4(&o_covs[tb * 1024 + i * 32 + (cb + c) * 4], sv);
      }
    }
    __syncthreads();

    // ACt = An @ SymM (SymM symmetric -> row dots)
    {
      int i = l >> 1, jb = (l & 1) * 16;
      f32x4 anr[8];
      #pragma unroll
      for (int k4 = 0; k4 < 8; ++k4) anr[k4] = An4[i * 9 + k4];
      #pragma unroll
      for (int c = 0; c < 4; ++c) {
        f32x4 av;
        #pragma unroll
        for (int mm = 0; mm < 4; ++mm) {
          int j = jb + c * 4 + mm;
          float acc = 0.f;
          #pragma unroll
          for (int k4 = 0; k4 < 8; ++k4) acc += dotv(anr[k4], Sy4[j * 9 + k4]);
          av[mm] = acc;
        }
        ACt4[i * 9 + (jb >> 2) + c] = av;
      }
    }
    __syncthreads();

    // M2 = ACt @ An^T -> Mt/MtT (reuse) + meanp' = An @ mean_t (lanes<32)
    {
      if (l < ZD) {
        float acc = 0.f;
        #pragma unroll
        for (int k4 = 0; k4 < 8; ++k4) acc += dotv(An4[l * 9 + k4], meant4[k4]);
        s.meanp[l] = acc;
        st_nt(&o_nmean[tb * ZD + l], acc);
      }
      int i = l >> 1, jb = (l & 1) * 16;
      f32x4 acr[8];
      #pragma unroll
      for (int k4 = 0; k4 < 8; ++k4) acr[k4] = ACt4[i * 9 + k4];
      #pragma unroll
      for (int c = 0; c < 4; ++c) {
        f32x4 mv;
        #pragma unroll
        for (int mm = 0; mm < 4; ++mm) {
          int j = jb + c * 4 + mm;
          float acc = 0.f;
          #pragma unroll
          for (int k4 = 0; k4 < 8; ++k4) acc += dotv(acr[k4], An4[j * 9 + k4]);
          mv[mm] = acc;
        }
        Mt4[i * 9 + (jb >> 2) + c] = mv;
        #pragma unroll
        for (int mm = 0; mm < 4; ++mm) s.MtT[(jb + c * 4 + mm) * 36 + i] = mv[mm];
      }
    }
    __syncthreads();

    // P' = 0.5(M2+M2^T) + Q -> P + ncovs out
    {
      int i = l >> 1, cb = (l & 1) * 4;
      #pragma unroll
      for (int c = 0; c < 4; ++c) {
        f32x4 pv = 0.5f * (Mt4[i * 9 + cb + c] + MtT4[i * 9 + cb + c]) + Q4[i * 9 + cb + c];
        P4[i * 9 + cb + c] = pv;
        st_nt4(&o_ncovs[tb * 1024 + i * 32 + (cb + c) * 4], pv);
      }
    }
    __syncthreads();
  }
}

extern "C" void kernel_launch(void* const* d_in, const int* in_sizes, int n_in,
                              void* d_out, int out_size, void* d_ws, size_t ws_size,
                              hipStream_t stream) {
  const float* as_ = (const float*)d_in[0];
  const float* AK = (const float*)d_in[1];
  const float* CK = (const float*)d_in[2];
  const float* QL = (const float*)d_in[3];
  const float* RL = (const float*)d_in[4];
  const float* initm = (const float*)d_in[5];
  const float* initc = (const float*)d_in[6];
  const float* Wih0 = (const float*)d_in[7];
  const float* Whh0 = (const float*)d_in[8];
  const float* bih0 = (const float*)d_in[9];
  const float* bhh0 = (const float*)d_in[10];
  const float* Wih1 = (const float*)d_in[11];
  const float* Whh1 = (const float*)d_in[12];
  const float* bih1 = (const float*)d_in[13];
  const float* bhh1 = (const float*)d_in[14];
  const float* Wout = (const float*)d_in[15];
  const float* bout = (const float*)d_in[16];
  float* ws = (float*)d_ws;
  float* out = (float*)d_out;

  ssm_prep_kernel<<<16, 256, 0, stream>>>(Wih0, Whh0, Wih1, Whh1, bih0, bhh0, bih1, bhh1,
                                          QL, RL, ws);
  ssm_lstm_kernel<<<B_SZ, NTHR, 0, stream>>>(as_, AK, CK, Wout, bout, ws, out);
  ssm_kalman_kernel<<<B_SZ, 64, 0, stream>>>(as_, initm, initc, ws, out);
}